// Round 10
// baseline (186.908 us; speedup 1.0000x reference)
//
#include <hip/hip_runtime.h>
#include <math.h>

#define T_N 100000
#define H_N 256
#define NT16 (T_N / 16)        // 6250 16-row tiles, exact
#define NBLK 1024              // k_at blocks (256 thr, 4 waves)
#define NSTREAM 512            // tile streams (NBLK*4/8)

typedef __attribute__((ext_vector_type(8))) __bf16 bf16x8;
typedef __attribute__((ext_vector_type(4))) float f32x4;

// ws layout (bytes):
//       0 : WmT bf16 [256][256]   (131072)
//  131072 : proj f32 [256]        (1024)
//  132096 : At   f32 [100000]     (400000)
//  532096 : part2 float2[256]     (2048)
//  536192 : s1g  f32[256]         (1024)
//  537216 : s0g  f32[256]         (1024)
//  538240 : lse  f32              (4)

__device__ __forceinline__ float tanh_fast(float x) {
    float e = __expf(2.0f * x);
    return 1.0f - 2.0f / (e + 1.0f);
}

// ---------------------------------------------------------------- prep
__global__ __launch_bounds__(256) void k_prep(const float* __restrict__ Wm,
                                              const float* __restrict__ hc,
                                              const float* __restrict__ W1,
                                              __bf16* __restrict__ WmT,
                                              float* __restrict__ proj,
                                              float* __restrict__ At,
                                              float* __restrict__ s1g,
                                              float* __restrict__ s0g) {
    const int j = blockIdx.x;
    const int t = threadIdx.x;
    WmT[j * H_N + t] = (__bf16)Wm[t * H_N + j];   // B^T, k-contiguous
    __shared__ float red[H_N];
    red[t] = hc[t] * W1[j * H_N + t];
    __syncthreads();
    for (int off = 128; off > 0; off >>= 1) {
        if (t < off) red[t] += red[t + off];
        __syncthreads();
    }
    if (t == 0) proj[j] = red[0];
    if (j == 0) { s1g[t] = 0.0f; s0g[t] = 0.0f; }
    // zero the At accumulator (atomicAdd target)
    for (int i = j * 256 + t; i < T_N; i += 256 * 256) At[i] = 0.0f;
}

// ---------------------------------------------------------------- fused At + ct partials
// 256 thr = 4 waves, fully independent (NO main-loop barriers). Wave global id
// W = L*4+w (L = XCD-chunked block id); cg = W&7 owns cols [32cg,32cg+32)
// (breg[8][2] = 64 VGPR, pinned); stream = W>>3 iterates 16-row tiles stride 512.
// A-fragments straight from global (L2-shared among the 8 cg-waves of a pair).
// At rows via global atomicAdd (8 adders). ct partials: own-p x fp32 Mt re-read.
__global__ __launch_bounds__(256, 3) void k_at(const float* __restrict__ Mt,
                                               const __bf16* __restrict__ WmT,
                                               const float* __restrict__ proj,
                                               const float* __restrict__ V,
                                               float* __restrict__ At,
                                               float* __restrict__ s1g,
                                               float* __restrict__ s0g) {
    const int tid = threadIdx.x;
    const int lane = tid & 63;
    const int w = tid >> 6;
    const int l15 = lane & 15;
    const int lg = lane >> 4;

    // XCD-chunked logical id: phys bid = 8x+e -> L = e*128+x, so L and L+1
    // share e (same XCD); the 8 cg-waves of a stream pair share L2.
    const int L = (blockIdx.x & 7) * 128 + (blockIdx.x >> 3);
    const int W = L * 4 + w;
    const int cg = W & 7;        // col group: cols [32cg, 32cg+32)
    const int stream = W >> 3;   // 0..511

    // ---- B fragments resident: breg[ks][fc], col n = 32cg+16fc+l15, k = 32ks+8lg
    f32x4 bregf[8][2];
#pragma unroll
    for (int ks = 0; ks < 8; ++ks)
#pragma unroll
        for (int fc = 0; fc < 2; ++fc) {
            bregf[ks][fc] = *(const f32x4*)(
                WmT + (32 * cg + 16 * fc + l15) * H_N + 32 * ks + 8 * lg);
            asm volatile("" : "+v"(bregf[ks][fc]));
        }
    float pj[2], vj[2];
#pragma unroll
    for (int fc = 0; fc < 2; ++fc) {
        const int n = 32 * cg + 16 * fc + l15;
        pj[fc] = proj[n];
        vj[fc] = V[n];
    }

    float s1a[4] = {0.f, 0.f, 0.f, 0.f};
    float s0a[4] = {0.f, 0.f, 0.f, 0.f};

    for (int tile = stream; tile < NT16; tile += NSTREAM) {
        const size_t base = (size_t)tile * 16 * H_N;
        const float* arow = Mt + base + (size_t)l15 * H_N;

        // ---- MFMA over K=256: load A frag per ks, 2 MFMA (interleaved for ILP)
        f32x4 acc0 = {0.f, 0.f, 0.f, 0.f};
        f32x4 acc1 = {0.f, 0.f, 0.f, 0.f};
#pragma unroll
        for (int ks = 0; ks < 8; ++ks) {
            const float4 a0 = *(const float4*)(arow + 32 * ks + 8 * lg);
            const float4 a1 = *(const float4*)(arow + 32 * ks + 8 * lg + 4);
            bf16x8 af;
            af[0] = (__bf16)a0.x; af[1] = (__bf16)a0.y;
            af[2] = (__bf16)a0.z; af[3] = (__bf16)a0.w;
            af[4] = (__bf16)a1.x; af[5] = (__bf16)a1.y;
            af[6] = (__bf16)a1.z; af[7] = (__bf16)a1.w;
            acc0 = __builtin_amdgcn_mfma_f32_16x16x32_bf16(
                af, __builtin_bit_cast(bf16x8, bregf[ks][0]), acc0, 0, 0, 0);
            acc1 = __builtin_amdgcn_mfma_f32_16x16x32_bf16(
                af, __builtin_bit_cast(bf16x8, bregf[ks][1]), acc1, 0, 0, 0);
        }

        // ---- epilogue: p[i] = row (4lg+i) partial over this wave's 32 cols
        float p[4];
#pragma unroll
        for (int i = 0; i < 4; ++i) {
            float q = tanh_fast(acc0[i] + pj[0]) * vj[0]
                    + tanh_fast(acc1[i] + pj[1]) * vj[1];
            q += __shfl_xor(q, 1);
            q += __shfl_xor(q, 2);
            q += __shfl_xor(q, 4);
            q += __shfl_xor(q, 8);
            p[i] = q;   // all 16 lanes of this lg group now hold row 4lg+i partial
        }
        // At accumulation: 4 lanes (l15==0) add their 4 rows
        if (l15 == 0) {
#pragma unroll
            for (int i = 0; i < 4; ++i)
                atomicAdd(&At[tile * 16 + 4 * lg + i], p[i]);
        }

        // ---- ct partials: exact, via own-wave p and fp32 rows (L2-hot re-read)
        const float* crow = Mt + base + lane * 4;
#pragma unroll
        for (int r = 0; r < 16; ++r) {
            const float atr = __shfl(p[r & 3], 16 * (r >> 2));
            const float4 x = *(const float4*)(crow + (size_t)r * H_N);
            s1a[0] += atr * x.x; s1a[1] += atr * x.y;
            s1a[2] += atr * x.z; s1a[3] += atr * x.w;
            if (cg == 0) {
                s0a[0] += x.x; s0a[1] += x.y;
                s0a[2] += x.z; s0a[3] += x.w;
            }
        }
    }

    // ---- block reduce (only sync in the kernel), then one atomic per col
    __shared__ float red[2][4][256];
#pragma unroll
    for (int q = 0; q < 4; ++q) {
        red[0][w][lane * 4 + q] = s1a[q];
        red[1][w][lane * 4 + q] = s0a[q];
    }
    __syncthreads();
    {
        float a1 = 0.f, a0 = 0.f;
#pragma unroll
        for (int g = 0; g < 4; ++g) {
            a1 += red[0][g][tid];
            a0 += red[1][g][tid];
        }
        atomicAdd(&s1g[tid], a1);
        if (a0 != 0.f) atomicAdd(&s0g[tid], a0);
    }
}

// ---------------------------------------------------------------- LSE stage 1
__global__ __launch_bounds__(256) void k_lse_part(const float* __restrict__ At,
                                                  float2* __restrict__ part) {
    const int tid = threadIdx.x;
    const int gid = blockIdx.x * 256 + tid;
    float m = -1e30f, s = 0.0f;
    for (int i = gid; i < T_N; i += 256 * 256) {
        const float x = At[i];
        if (x > m) { s = s * __expf(m - x) + 1.0f; m = x; }
        else s += __expf(x - m);
    }
    __shared__ float ms[256], ss[256];
    ms[tid] = m; ss[tid] = s;
    __syncthreads();
    for (int off = 128; off > 0; off >>= 1) {
        if (tid < off) {
            const float m2 = ms[tid + off], s2 = ss[tid + off];
            const float M = fmaxf(ms[tid], m2);
            ss[tid] = ss[tid] * __expf(ms[tid] - M) + s2 * __expf(m2 - M);
            ms[tid] = M;
        }
        __syncthreads();
    }
    if (tid == 0) part[blockIdx.x] = make_float2(ms[0], ss[0]);
}

// ---------------------------------------------------------------- final: LSE + ct
__global__ __launch_bounds__(256) void k_final(const float2* __restrict__ part2,
                                               const float* __restrict__ s1g,
                                               const float* __restrict__ s0g,
                                               float* __restrict__ lse,
                                               float* __restrict__ out) {
    const int tid = threadIdx.x;
    __shared__ float ms[256], ss[256];
    const float2 p = part2[tid];
    ms[tid] = p.x; ss[tid] = p.y;
    __syncthreads();
    for (int off = 128; off > 0; off >>= 1) {
        if (tid < off) {
            const float m2 = ms[tid + off], s2 = ss[tid + off];
            const float M = fmaxf(ms[tid], m2);
            ss[tid] = ss[tid] * __expf(ms[tid] - M) + s2 * __expf(m2 - M);
            ms[tid] = M;
        }
        __syncthreads();
    }
    __shared__ float Ls;
    if (tid == 0) { Ls = ms[0] + logf(ss[0]); *lse = Ls; }
    __syncthreads();
    out[T_N + tid] = s1g[tid] - Ls * s0g[tid];
}

// ---------------------------------------------------------------- alphat = At - LSE
__global__ __launch_bounds__(256) void k_alpha(const float* __restrict__ At,
                                               const float* __restrict__ lse,
                                               float* __restrict__ out) {
    const float L = *lse;
    const int i4 = blockIdx.x * 256 + threadIdx.x;
    if (i4 < T_N / 4) {
        float4 a = *(const float4*)(At + i4 * 4);
        a.x -= L; a.y -= L; a.z -= L; a.w -= L;
        *(float4*)(out + i4 * 4) = a;
    }
}

// ----------------------------------------------------------------
extern "C" void kernel_launch(void* const* d_in, const int* in_sizes, int n_in,
                              void* d_out, int out_size, void* d_ws, size_t ws_size,
                              hipStream_t stream) {
    const float* inputs = (const float*)d_in[0];  // (T, H)
    const float* hc     = (const float*)d_in[1];  // (1, H)
    const float* Wm     = (const float*)d_in[2];  // (H, H)
    const float* V      = (const float*)d_in[3];  // (H, 1)
    const float* W1     = (const float*)d_in[4];  // (H, H)
    float* out = (float*)d_out;                   // [alphat (T) | ct (H)]

    char* ws = (char*)d_ws;
    __bf16* WmT  = (__bf16*)ws;
    float* proj  = (float*)(ws + 131072);
    float* At    = (float*)(ws + 132096);
    float2* p2   = (float2*)(ws + 532096);
    float* s1g   = (float*)(ws + 536192);
    float* s0g   = (float*)(ws + 537216);
    float* lse   = (float*)(ws + 538240);

    k_prep<<<256, 256, 0, stream>>>(Wm, hc, W1, WmT, proj, At, s1g, s0g);
    k_at<<<NBLK, 256, 0, stream>>>(inputs, WmT, proj, V, At, s1g, s0g);
    k_lse_part<<<256, 256, 0, stream>>>(At, p2);
    k_final<<<1, 256, 0, stream>>>(p2, s1g, s0g, lse, out);
    k_alpha<<<98, 256, 0, stream>>>(At, lse, out);
}